// Round 1
// baseline (413.085 us; speedup 1.0000x reference)
//
#include <hip/hip_runtime.h>
#include <hip/hip_bf16.h>
#include <stdint.h>
#include <stddef.h>

// QuestionSpecificMLP R6: software-pipelined fused trunk.
//  - global_load_lds (width=16) double-buffered weight staging, 1 barrier/K-step
//  - x prefetched one K-step ahead in registers (full unroll, static indexing)
//  - packed v_cvt_pk_bf16_f32 conversions (via __float22bfloat162_rn)
//  - scan_k launch removed: scatter blocks recompute the 2048-bin scan locally

typedef short s8v __attribute__((ext_vector_type(8)));   // 8 bf16 (4 VGPRs)
typedef float f4v __attribute__((ext_vector_type(4)));   // MFMA acc
typedef float f4a __attribute__((ext_vector_type(4), aligned(4)));  // 4B-aligned float4

typedef const void __attribute__((address_space(1))) *gas1_t;
typedef void __attribute__((address_space(3))) *las3_t;

namespace {
constexpr int kDin = 385;
constexpr int kDh  = 192;
constexpr int kQ   = 1000;
constexpr int kC   = 16;
constexpr int BM   = 64;
constexpr int NT   = 256;
constexpr int NK1  = 13;          // ceil(385/32), zero-padded
constexpr int NK2  = 6;           // 192/32
constexpr int CHUNK = 12 * 64 * 8;   // 6144 bf16 (12288 B) per swizzled k-chunk
constexpr int H2   = 200;         // bf16 stride for h / feat rows

// workspace layout (bytes)
constexpr size_t WS_W1   = 0;        // 159744
constexpr size_t WS_W2   = 163840;   // 73728
constexpr size_t WS_HIST = 245760;   // 2048*4
constexpr size_t WS_CUR  = 253952;   // 2048*4 (rank counters)
constexpr size_t WS_PERM = 262144;   // 131072*4 -> ends at 768 KB
}

__device__ __forceinline__ unsigned short f2bf(float f) {
  unsigned int u = __float_as_uint(f);
  u = u + 0x7fffu + ((u >> 16) & 1u);       // RNE (non-NaN inputs)
  return (unsigned short)(u >> 16);
}

// packed pair: low 16 = bf16(lo), high 16 = bf16(hi); lowers to v_cvt_pk_bf16_f32
__device__ __forceinline__ unsigned int pk2(float lo, float hi) {
  union { __hip_bfloat162 h2; unsigned int u; } cv;
  cv.h2 = __float22bfloat162_rn(make_float2(lo, hi));
  return cv.u;
}

union s8u { s8v s; unsigned int u[4]; };

// ---- combined prep: histogram + both weight swizzles ---------------------
__device__ __forceinline__ void swz_one(const float* W, int K, int i,
                                        unsigned short* out) {
  int k = i / kDh;
  int c = i - k * kDh;
  float v = (k < K) ? W[(size_t)k * kDh + c] : 0.f;
  int oi = (k >> 5) * CHUNK + (((c >> 4) * 64 + ((k >> 3) & 3) * 16 + (c & 15)) << 3)
         + (k & 7);
  out[oi] = f2bf(v);
}

__global__ void combo_prep(const int* __restrict__ qid, const int* __restrict__ isc,
                           int B, int nbH,
                           const float* __restrict__ W1, const float* __restrict__ W2,
                           int* __restrict__ hist,
                           unsigned short* __restrict__ W1sw,
                           unsigned short* __restrict__ W2sw) {
  int bid = blockIdx.x;
  if (bid < nbH) {
    int i = bid * 256 + threadIdx.x;
    if (i < B) atomicAdd(&hist[qid[i] + isc[i] * kQ], 1);
  } else if (bid < nbH + 312) {                       // 312*256 = 416*192
    swz_one(W1, kDin, (bid - nbH) * 256 + threadIdx.x, W1sw);
  } else {                                            // 144*256 = 192*192
    swz_one(W2, kDh, (bid - nbH - 312) * 256 + threadIdx.x, W2sw);
  }
}

// ---- scan folded into scatter: each block recomputes the 2048-bin scan ----
__global__ __launch_bounds__(256)
void scatter2(const int* __restrict__ qid, const int* __restrict__ isc, int B,
              const int* __restrict__ hist, int* __restrict__ rank_ctr,
              int* __restrict__ perm) {
  __shared__ int sh[2048];
  __shared__ int ssum[256];
  int t = threadIdx.x;
  int4 a = ((const int4*)hist)[t * 2];
  int4 b = ((const int4*)hist)[t * 2 + 1];
  int s1 = a.x + a.y, s2 = s1 + a.z, s3 = s2 + a.w;
  int s4 = s3 + b.x, s5 = s4 + b.y, s6 = s5 + b.z, s7 = s6 + b.w;
  ssum[t] = s7;
  __syncthreads();
  #pragma unroll
  for (int d = 1; d < 256; d <<= 1) {
    int xv = (t >= d) ? ssum[t - d] : 0;
    __syncthreads();
    ssum[t] += xv;
    __syncthreads();
  }
  int base = ssum[t] - s7;                 // exclusive prefix over 8-bin groups
  sh[t * 8 + 0] = base;
  sh[t * 8 + 1] = base + a.x;
  sh[t * 8 + 2] = base + s1;
  sh[t * 8 + 3] = base + s2;
  sh[t * 8 + 4] = base + s3;
  sh[t * 8 + 5] = base + s4;
  sh[t * 8 + 6] = base + s5;
  sh[t * 8 + 7] = base + s6;
  __syncthreads();
  int i = blockIdx.x * 256 + t;
  if (i < B) {
    int h = qid[i] + isc[i] * kQ;
    int pos = sh[h] + atomicAdd(&rank_ctr[h], 1);
    perm[pos] = i;
  }
}

// ---- async weight chunk staging: linear LDS, wave-uniform base -----------
__device__ __forceinline__ void stage_chunk(const unsigned short* gsrc,
                                            unsigned short* lbase, int tid) {
  const char* g = (const char*)gsrc + (size_t)tid * 16;
  char* l = (char*)lbase + ((tid >> 6) << 10);        // wave-uniform per wave
  __builtin_amdgcn_global_load_lds((gas1_t)g,          (las3_t)l,          16, 0, 0);
  __builtin_amdgcn_global_load_lds((gas1_t)(g + 4096), (las3_t)(l + 4096), 16, 0, 0);
  __builtin_amdgcn_global_load_lds((gas1_t)(g + 8192), (las3_t)(l + 8192), 16, 0, 0);
}

// ---- main fused kernel ---------------------------------------------------
__global__ __launch_bounds__(NT, 3)
void fused_qmlp6(const float* __restrict__ x,
                 const int*   __restrict__ qid,
                 const int*   __restrict__ isc,
                 const float* __restrict__ b1,
                 const float* __restrict__ b2,
                 const float* __restrict__ Wh,
                 const float* __restrict__ bh,
                 const unsigned short* __restrict__ W1sw,
                 const unsigned short* __restrict__ W2sw,
                 const int*   __restrict__ perm,
                 float* __restrict__ out) {
  __shared__ __align__(16) unsigned short hS[BM * H2];   // 25600 B
  __shared__ __align__(16) unsigned short bS[2 * CHUNK]; // 24576 B double buffer
  __shared__ int permS[BM];
  __shared__ int idxS[BM];

  const int tid  = threadIdx.x;
  const int lane = tid & 63, wid = tid >> 6;
  const int m = lane & 15, quad = lane >> 4;
  const int rh = wid & 1, ch = wid >> 1;
  const int row0 = blockIdx.x * BM;

  if (tid < BM) {
    int p = perm[row0 + tid];
    permS[tid] = p;
    idxS[tid] = qid[p] + isc[p] * kQ;
  }
  stage_chunk(W1sw, bS, tid);              // chunk 0 -> bS[0]
  __syncthreads();                         // permS visible + chunk 0 resident

  const float* px0 = x + (size_t)permS[rh * 32 + m] * kDin;
  const float* px1 = x + (size_t)permS[rh * 32 + m + 16] * kDin;

  f4v acc0[6], acc1[6];
  #pragma unroll
  for (int t = 0; t < 6; ++t) {
    acc0[t] = (f4v){0.f, 0.f, 0.f, 0.f};
    acc1[t] = (f4v){0.f, 0.f, 0.f, 0.f};
  }

  // x prefetch registers (current K-step)
  f4a c0, c1, c2, c3;
  {
    const float* q0 = px0 + quad * 8;
    const float* q1 = px1 + quad * 8;
    c0 = *(const f4a*)q0; c1 = *(const f4a*)(q0 + 4);
    c2 = *(const f4a*)q1; c3 = *(const f4a*)(q1 + 4);
  }
  float tl0 = 0.f, tl1 = 0.f;

  // ---------------- layer 1: h = relu(x @ W1 + b1), K padded to 416 --------
  #pragma unroll
  for (int kk = 0; kk < NK1; ++kk) {
    const int nj = kk + 1;                              // next chunk: 1..13
    const unsigned short* np = (nj < NK1)
        ? W1sw + (size_t)nj * CHUNK
        : W2sw;                                         // nj==13 -> W2 chunk 0
    stage_chunk(np, bS + (nj & 1) * CHUNK, tid);        // hides under MFMAs

    f4a n0, n1, n2, n3;
    if (kk < NK1 - 2) {                                 // prefetch x for kk+1
      const float* q0 = px0 + nj * 32 + quad * 8;
      const float* q1 = px1 + nj * 32 + quad * 8;
      n0 = *(const f4a*)q0; n1 = *(const f4a*)(q0 + 4);
      n2 = *(const f4a*)q1; n3 = *(const f4a*)(q1 + 4);
    } else if (kk == NK1 - 2) {                         // tail: only k==384
      tl0 = (quad == 0) ? px0[384] : 0.f;
      tl1 = (quad == 0) ? px1[384] : 0.f;
    }

    s8v a0, a1;
    if (kk < NK1 - 1) {
      s8u ua, ub;
      ua.u[0] = pk2(c0[0], c0[1]); ua.u[1] = pk2(c0[2], c0[3]);
      ua.u[2] = pk2(c1[0], c1[1]); ua.u[3] = pk2(c1[2], c1[3]);
      ub.u[0] = pk2(c2[0], c2[1]); ub.u[1] = pk2(c2[2], c2[3]);
      ub.u[2] = pk2(c3[0], c3[1]); ub.u[3] = pk2(c3[2], c3[3]);
      a0 = ua.s; a1 = ub.s;
    } else {
      a0 = (s8v){0,0,0,0,0,0,0,0};
      a1 = (s8v){0,0,0,0,0,0,0,0};
      a0[0] = (short)f2bf(tl0);
      a1[0] = (short)f2bf(tl1);
    }

    const unsigned short* bBuf = bS + (kk & 1) * CHUNK;
    #pragma unroll
    for (int t = 0; t < 6; ++t) {
      s8v b = *(const s8v*)&bBuf[((ch * 6 + t) * 64 + lane) * 8];
      acc0[t] = __builtin_amdgcn_mfma_f32_16x16x32_bf16(a0, b, acc0[t], 0, 0, 0);
      acc1[t] = __builtin_amdgcn_mfma_f32_16x16x32_bf16(a1, b, acc1[t], 0, 0, 0);
    }
    __syncthreads();   // drains next-chunk loads; frees bBuf for reuse
    if (kk < NK1 - 2) { c0 = n0; c1 = n1; c2 = n2; c3 = n3; }
  }

  // epilogue 1: bias + relu, h -> LDS bf16 row-major
  #pragma unroll
  for (int t = 0; t < 6; ++t) {
    int c = ch * 96 + t * 16 + m;
    float bb = b1[c];
    #pragma unroll
    for (int r4 = 0; r4 < 4; ++r4) {
      int r = rh * 32 + quad * 4 + r4;
      float v0 = acc0[t][r4] + bb; v0 = v0 > 0.f ? v0 : 0.f;
      hS[r * H2 + c] = f2bf(v0);
      float v1 = acc1[t][r4] + bb; v1 = v1 > 0.f ? v1 : 0.f;
      hS[(r + 16) * H2 + c] = f2bf(v1);
      acc0[t][r4] = 0.f;
      acc1[t][r4] = 0.f;
    }
  }
  __syncthreads();     // hS visible to all waves (W2 chunk 0 already resident)

  // ---------------- layer 2: feat = relu(h @ W2 + b2) ----------------------
  const int ar0 = (rh * 32 + m) * H2;
  #pragma unroll
  for (int k2 = 0; k2 < NK2; ++k2) {
    if (k2 < NK2 - 1)                                    // stage W2 chunk k2+1
      stage_chunk(W2sw + (size_t)(k2 + 1) * CHUNK,
                  bS + ((14 + k2) & 1) * CHUNK, tid);

    s8v a0 = *(const s8v*)&hS[ar0 + k2 * 32 + quad * 8];
    s8v a1 = *(const s8v*)&hS[ar0 + 16 * H2 + k2 * 32 + quad * 8];
    const unsigned short* bBuf = bS + ((13 + k2) & 1) * CHUNK;
    #pragma unroll
    for (int t = 0; t < 6; ++t) {
      s8v b = *(const s8v*)&bBuf[((ch * 6 + t) * 64 + lane) * 8];
      acc0[t] = __builtin_amdgcn_mfma_f32_16x16x32_bf16(a0, b, acc0[t], 0, 0, 0);
      acc1[t] = __builtin_amdgcn_mfma_f32_16x16x32_bf16(a1, b, acc1[t], 0, 0, 0);
    }
    __syncthreads();
  }

  // epilogue 2: bias + relu, feat (bf16) overwrites h region
  #pragma unroll
  for (int t = 0; t < 6; ++t) {
    int c = ch * 96 + t * 16 + m;
    float bb = b2[c];
    #pragma unroll
    for (int r4 = 0; r4 < 4; ++r4) {
      int r = rh * 32 + quad * 4 + r4;
      float v0 = acc0[t][r4] + bb;
      hS[r * H2 + c] = f2bf(v0 > 0.f ? v0 : 0.f);
      float v1 = acc1[t][r4] + bb;
      hS[(r + 16) * H2 + c] = f2bf(v1 > 0.f ? v1 : 0.f);
    }
  }
  __syncthreads();

  // ---------------- routed head via MFMA, one pass per distinct head -------
  {
    const int w16 = wid * 16;
    const int hm = idxS[w16 + m];             // head of this lane's A-row
    unsigned rem = 0xFFFFu;
    while (rem) {
      int r0 = (int)__builtin_ctz(rem);
      int h = idxS[w16 + r0];                 // uniform (LDS broadcast)
      unsigned long long bal = __ballot(hm == h);
      unsigned mask16 = (unsigned)(bal & 0xFFFFu);
      rem &= ~mask16;
      bool valid = (hm == h);

      const float* wq = Wh + ((size_t)h * kC + m) * kDh + quad * 8;
      f4v acc = (f4v){0.f, 0.f, 0.f, 0.f};
      #pragma unroll
      for (int kk = 0; kk < 6; ++kk) {
        float4 wlo = *(const float4*)(wq + kk * 32);
        float4 whi = *(const float4*)(wq + kk * 32 + 4);
        s8u ub;
        ub.u[0] = pk2(wlo.x, wlo.y);
        ub.u[1] = pk2(wlo.z, wlo.w);
        ub.u[2] = pk2(whi.x, whi.y);
        ub.u[3] = pk2(whi.z, whi.w);
        s8v bfr = ub.s;
        s8v afr = *(const s8v*)&hS[(w16 + m) * H2 + kk * 32 + quad * 8];
        if (!valid) afr = (s8v){0,0,0,0,0,0,0,0};
        acc = __builtin_amdgcn_mfma_f32_16x16x32_bf16(afr, bfr, acc, 0, 0, 0);
      }
      float bhv = bh[(size_t)h * kC + m];
      #pragma unroll
      for (int reg = 0; reg < 4; ++reg) {
        int r = quad * 4 + reg;
        if ((mask16 >> r) & 1u)
          out[(size_t)permS[w16 + r] * kC + m] = acc[reg] + bhv;
      }
    }
  }
}

extern "C" void kernel_launch(void* const* d_in, const int* in_sizes, int n_in,
                              void* d_out, int out_size, void* d_ws, size_t ws_size,
                              hipStream_t stream) {
  const float* x  = (const float*)d_in[0];
  const int*   qd = (const int*)  d_in[1];
  const int*   ic = (const int*)  d_in[2];
  const float* W1 = (const float*)d_in[3];
  const float* b1 = (const float*)d_in[4];
  const float* W2 = (const float*)d_in[5];
  const float* b2 = (const float*)d_in[6];
  const float* Wh = (const float*)d_in[7];
  const float* bh = (const float*)d_in[8];
  float* out = (float*)d_out;

  char* ws = (char*)d_ws;
  unsigned short* W1sw = (unsigned short*)(ws + WS_W1);
  unsigned short* W2sw = (unsigned short*)(ws + WS_W2);
  int* hist = (int*)(ws + WS_HIST);
  int* rank = (int*)(ws + WS_CUR);
  int* perm = (int*)(ws + WS_PERM);

  int B = in_sizes[1];   // 131072
  int nbH = (B + 255) / 256;

  hipMemsetAsync(hist, 0, 4096 * sizeof(int), stream);   // hist + rank_ctr
  combo_prep<<<nbH + 312 + 144, 256, 0, stream>>>(qd, ic, B, nbH, W1, W2,
                                                  hist, W1sw, W2sw);
  scatter2<<<(B + 255) / 256, 256, 0, stream>>>(qd, ic, B, hist, rank, perm);

  fused_qmlp6<<<B / BM, NT, 0, stream>>>(x, qd, ic, b1, b2, Wh, bh,
                                         W1sw, W2sw, perm, out);
}

// Round 3
// 392.016 us; speedup vs baseline: 1.0537x; 1.0537x over previous
//
#include <hip/hip_runtime.h>
#include <hip/hip_bf16.h>
#include <stdint.h>
#include <stddef.h>

// QuestionSpecificMLP R8:
//  - fused: NT=512 / BM=64, single-buffered weight LDS (38400 B total) ->
//    4 blocks/CU x 8 waves = 32 waves/CU (occupancy cap). R5<->R6 evidence:
//    latency-bound, perf ~ resident waves. Keeps gload_lds staging + packed
//    cvt + x-prefetch from R6.
//  - prep: reverted to the PROVEN non-cooperative chain (memset + combo_prep
//    + scatter2). R7's cooperative prep is the prime suspect for the
//    container crash (graph-capture + hipLaunchCooperativeKernel -> prep
//    never ran -> garbage perm -> OOB reads).

typedef short s8v __attribute__((ext_vector_type(8)));   // 8 bf16 (4 VGPRs)
typedef float f4v __attribute__((ext_vector_type(4)));   // MFMA acc
typedef float f4a __attribute__((ext_vector_type(4), aligned(4)));  // 4B-aligned float4

typedef const void __attribute__((address_space(1))) *gas1_t;
typedef void __attribute__((address_space(3))) *las3_t;

namespace {
constexpr int kDin = 385;
constexpr int kDh  = 192;
constexpr int kQ   = 1000;
constexpr int kC   = 16;
constexpr int BM   = 64;
constexpr int NT   = 512;
constexpr int NK1  = 13;          // ceil(385/32), zero-padded
constexpr int NK2  = 6;           // 192/32
constexpr int CHUNK = 12 * 64 * 8;   // 6144 bf16 (12288 B) per swizzled k-chunk
constexpr int H2   = 200;         // bf16 stride for h / feat rows

// workspace layout (bytes)
constexpr size_t WS_W1   = 0;        // 159744
constexpr size_t WS_W2   = 163840;   // 73728
constexpr size_t WS_HIST = 245760;   // 2048*4 counts
constexpr size_t WS_CUR  = 253952;   // 2048*4 rank counters
constexpr size_t WS_PERM = 262144;   // 131072*4 -> ends at 768 KB
}

__device__ __forceinline__ unsigned short f2bf(float f) {
  unsigned int u = __float_as_uint(f);
  u = u + 0x7fffu + ((u >> 16) & 1u);       // RNE (non-NaN inputs)
  return (unsigned short)(u >> 16);
}

// packed pair: low 16 = bf16(lo), high 16 = bf16(hi); lowers to v_cvt_pk_bf16_f32
__device__ __forceinline__ unsigned int pk2(float lo, float hi) {
  union { __hip_bfloat162 h2; unsigned int u; } cv;
  cv.h2 = __float22bfloat162_rn(make_float2(lo, hi));
  return cv.u;
}

union s8u { s8v s; unsigned int u[4]; };

// ---- combined prep: histogram + both weight swizzles ---------------------
__device__ __forceinline__ void swz_one(const float* W, int K, int i,
                                        unsigned short* out) {
  int k = i / kDh;
  int c = i - k * kDh;
  float v = (k < K) ? W[(size_t)k * kDh + c] : 0.f;
  int oi = (k >> 5) * CHUNK + (((c >> 4) * 64 + ((k >> 3) & 3) * 16 + (c & 15)) << 3)
         + (k & 7);
  out[oi] = f2bf(v);
}

__global__ void combo_prep(const int* __restrict__ qid, const int* __restrict__ isc,
                           int B, int nbH,
                           const float* __restrict__ W1, const float* __restrict__ W2,
                           int* __restrict__ hist,
                           unsigned short* __restrict__ W1sw,
                           unsigned short* __restrict__ W2sw) {
  int bid = blockIdx.x;
  if (bid < nbH) {
    int i = bid * 256 + threadIdx.x;
    if (i < B) atomicAdd(&hist[qid[i] + isc[i] * kQ], 1);
  } else if (bid < nbH + 312) {                       // 312*256 = 416*192
    swz_one(W1, kDin, (bid - nbH) * 256 + threadIdx.x, W1sw);
  } else {                                            // 144*256 = 192*192
    swz_one(W2, kDh, (bid - nbH - 312) * 256 + threadIdx.x, W2sw);
  }
}

// ---- scan folded into scatter: each block recomputes the 2048-bin scan ----
__global__ __launch_bounds__(256)
void scatter2(const int* __restrict__ qid, const int* __restrict__ isc, int B,
              const int* __restrict__ hist, int* __restrict__ rank_ctr,
              int* __restrict__ perm) {
  __shared__ int sh[2048];
  __shared__ int ssum[256];
  int t = threadIdx.x;
  int4 a = ((const int4*)hist)[t * 2];
  int4 b = ((const int4*)hist)[t * 2 + 1];
  int s1 = a.x + a.y, s2 = s1 + a.z, s3 = s2 + a.w;
  int s4 = s3 + b.x, s5 = s4 + b.y, s6 = s5 + b.z, s7 = s6 + b.w;
  ssum[t] = s7;
  __syncthreads();
  #pragma unroll
  for (int d = 1; d < 256; d <<= 1) {
    int xv = (t >= d) ? ssum[t - d] : 0;
    __syncthreads();
    ssum[t] += xv;
    __syncthreads();
  }
  int base = ssum[t] - s7;                 // exclusive prefix over 8-bin groups
  sh[t * 8 + 0] = base;
  sh[t * 8 + 1] = base + a.x;
  sh[t * 8 + 2] = base + s1;
  sh[t * 8 + 3] = base + s2;
  sh[t * 8 + 4] = base + s3;
  sh[t * 8 + 5] = base + s4;
  sh[t * 8 + 6] = base + s5;
  sh[t * 8 + 7] = base + s6;
  __syncthreads();
  int i = blockIdx.x * 256 + t;
  if (i < B) {
    int h = qid[i] + isc[i] * kQ;
    int pos = sh[h] + atomicAdd(&rank_ctr[h], 1);
    perm[pos] = i;
  }
}

// ---- main fused kernel ---------------------------------------------------
__global__ __launch_bounds__(NT, 8)
void fused_qmlp8(const float* __restrict__ x,
                 const int*   __restrict__ qid,
                 const int*   __restrict__ isc,
                 const float* __restrict__ b1,
                 const float* __restrict__ b2,
                 const float* __restrict__ Wh,
                 const float* __restrict__ bh,
                 const unsigned short* __restrict__ W1sw,
                 const unsigned short* __restrict__ W2sw,
                 const int*   __restrict__ perm,
                 float* __restrict__ out) {
  __shared__ __align__(16) unsigned short hS[BM * H2];   // 25600 B
  __shared__ __align__(16) unsigned short bS[CHUNK];     // 12288 B single buffer
  __shared__ int permS[BM];
  __shared__ int idxS[BM];

  const int tid  = threadIdx.x;
  const int lane = tid & 63, wid = tid >> 6;   // wid 0..7
  const int m = lane & 15, quad = lane >> 4;
  const int rh = wid >> 1, ch = wid & 1;       // row-group 0..3, col-half
  const int row0 = blockIdx.x * BM;

  // stage W1 chunk 0: 512 thr x 16B = 8192 B; threads<256 cover last 4096 B
  {
    const char* g = (const char*)W1sw + (size_t)tid * 16;
    char* l = (char*)bS + ((tid >> 6) << 10);
    __builtin_amdgcn_global_load_lds((gas1_t)g, (las3_t)l, 16, 0, 0);
    if (tid < 256)
      __builtin_amdgcn_global_load_lds((gas1_t)(g + 8192), (las3_t)(l + 8192),
                                       16, 0, 0);
  }
  if (tid < BM) {
    int p = perm[row0 + tid];
    permS[tid] = p;
    idxS[tid] = qid[p] + isc[p] * kQ;
  }
  __syncthreads();                       // permS visible + chunk 0 resident

  const float* px = x + (size_t)permS[rh * 16 + m] * kDin;

  f4v acc[6];
  #pragma unroll
  for (int t = 0; t < 6; ++t) acc[t] = (f4v){0.f, 0.f, 0.f, 0.f};

  f4a c0 = *(const f4a*)(px + quad * 8);
  f4a c1 = *(const f4a*)(px + quad * 8 + 4);
  float tl = 0.f;

  // ------------- layer 1: h = relu(x @ W1 + b1), K padded to 416 ----------
  #pragma unroll
  for (int kk = 0; kk < NK1; ++kk) {
    s8v a;
    if (kk < NK1 - 1) {
      s8u ua;
      ua.u[0] = pk2(c0[0], c0[1]); ua.u[1] = pk2(c0[2], c0[3]);
      ua.u[2] = pk2(c1[0], c1[1]); ua.u[3] = pk2(c1[2], c1[3]);
      a = ua.s;
    } else {                              // only k==384 valid (quad 0, j 0)
      a = (s8v){0,0,0,0,0,0,0,0};
      a[0] = (short)f2bf(tl);             // tl==0 for quad!=0
    }

    #pragma unroll
    for (int t = 0; t < 6; ++t) {
      s8v b = *(const s8v*)&bS[((ch * 6 + t) * 64 + lane) * 8];
      acc[t] = __builtin_amdgcn_mfma_f32_16x16x32_bf16(a, b, acc[t], 0, 0, 0);
    }
    __syncthreads();                      // all waves done reading chunk kk

    // stage next chunk into the same buffer (W2 chunk 0 after last W1 chunk)
    {
      const unsigned short* np = (kk < NK1 - 1)
          ? W1sw + (size_t)(kk + 1) * CHUNK : W2sw;
      const char* g = (const char*)np + (size_t)tid * 16;
      char* l = (char*)bS + ((tid >> 6) << 10);
      __builtin_amdgcn_global_load_lds((gas1_t)g, (las3_t)l, 16, 0, 0);
      if (tid < 256)
        __builtin_amdgcn_global_load_lds((gas1_t)(g + 8192), (las3_t)(l + 8192),
                                         16, 0, 0);
    }
    if (kk < NK1 - 2) {                   // prefetch x for next iter
      c0 = *(const f4a*)(px + (kk + 1) * 32 + quad * 8);
      c1 = *(const f4a*)(px + (kk + 1) * 32 + quad * 8 + 4);
    } else if (kk == NK1 - 2) {
      tl = (quad == 0) ? px[384] : 0.f;
    }
    if (kk == NK1 - 1) {
      // epilogue 1 overlaps the W2-chunk-0 stage: bias + relu -> hS bf16
      #pragma unroll
      for (int t = 0; t < 6; ++t) {
        int c = ch * 96 + t * 16 + m;
        float bb = b1[c];
        #pragma unroll
        for (int r4 = 0; r4 < 4; ++r4) {
          int r = rh * 16 + quad * 4 + r4;
          float v0 = acc[t][r4] + bb;
          hS[r * H2 + c] = f2bf(v0 > 0.f ? v0 : 0.f);
          acc[t][r4] = 0.f;
        }
      }
    }
    __syncthreads();                      // drains stage (+x loads)
  }

  // ------------- layer 2: feat = relu(h @ W2 + b2) ------------------------
  const int ar0 = (rh * 16 + m) * H2;
  #pragma unroll
  for (int k2 = 0; k2 < NK2; ++k2) {
    s8v a = *(const s8v*)&hS[ar0 + k2 * 32 + quad * 8];
    #pragma unroll
    for (int t = 0; t < 6; ++t) {
      s8v b = *(const s8v*)&bS[((ch * 6 + t) * 64 + lane) * 8];
      acc[t] = __builtin_amdgcn_mfma_f32_16x16x32_bf16(a, b, acc[t], 0, 0, 0);
    }
    __syncthreads();                      // chunk k2 reads + hS reads done
    if (k2 < NK2 - 1) {
      const char* g = (const char*)(W2sw + (size_t)(k2 + 1) * CHUNK)
                    + (size_t)tid * 16;
      char* l = (char*)bS + ((tid >> 6) << 10);
      __builtin_amdgcn_global_load_lds((gas1_t)g, (las3_t)l, 16, 0, 0);
      if (tid < 256)
        __builtin_amdgcn_global_load_lds((gas1_t)(g + 8192), (las3_t)(l + 8192),
                                         16, 0, 0);
    } else {
      // epilogue 2: bias + relu, feat overwrites h region (reads fenced above)
      #pragma unroll
      for (int t = 0; t < 6; ++t) {
        int c = ch * 96 + t * 16 + m;
        float bb = b2[c];
        #pragma unroll
        for (int r4 = 0; r4 < 4; ++r4) {
          int r = rh * 16 + quad * 4 + r4;
          float v0 = acc[t][r4] + bb;
          hS[r * H2 + c] = f2bf(v0 > 0.f ? v0 : 0.f);
        }
      }
    }
    __syncthreads();
  }

  // ------------- routed head via MFMA, runs split by parity across ch -----
  {
    const int w16 = rh * 16;
    const int hm = idxS[w16 + m];             // head of this lane's A-row
    unsigned rem = 0xFFFFu;
    int runIdx = 0;
    while (rem) {
      int r0 = (int)__builtin_ctz(rem);
      int h = idxS[w16 + r0];                 // uniform (LDS broadcast)
      unsigned long long bal = __ballot(hm == h);
      unsigned mask16 = (unsigned)(bal & 0xFFFFu);
      rem &= ~mask16;
      if ((runIdx & 1) == ch) {               // parity-split runs across pair
        const float* wq = Wh + ((size_t)h * kC + m) * kDh + quad * 8;
        f4v acch = (f4v){0.f, 0.f, 0.f, 0.f};
        #pragma unroll
        for (int kk = 0; kk < 6; ++kk) {
          float4 wlo = *(const float4*)(wq + kk * 32);
          float4 whi = *(const float4*)(wq + kk * 32 + 4);
          s8u ub;
          ub.u[0] = pk2(wlo.x, wlo.y);
          ub.u[1] = pk2(wlo.z, wlo.w);
          ub.u[2] = pk2(whi.x, whi.y);
          ub.u[3] = pk2(whi.z, whi.w);
          s8v bfr = ub.s;
          s8v afr = *(const s8v*)&hS[(w16 + m) * H2 + kk * 32 + quad * 8];
          if (hm != h) afr = (s8v){0,0,0,0,0,0,0,0};
          acch = __builtin_amdgcn_mfma_f32_16x16x32_bf16(afr, bfr, acch, 0, 0, 0);
        }
        float bhv = bh[(size_t)h * kC + m];
        #pragma unroll
        for (int reg = 0; reg < 4; ++reg) {
          int r = quad * 4 + reg;
          if ((mask16 >> r) & 1u)
            out[(size_t)permS[w16 + r] * kC + m] = acch[reg] + bhv;
        }
      }
      runIdx++;
    }
  }
}

extern "C" void kernel_launch(void* const* d_in, const int* in_sizes, int n_in,
                              void* d_out, int out_size, void* d_ws, size_t ws_size,
                              hipStream_t stream) {
  const float* x  = (const float*)d_in[0];
  const int*   qd = (const int*)  d_in[1];
  const int*   ic = (const int*)  d_in[2];
  const float* W1 = (const float*)d_in[3];
  const float* b1 = (const float*)d_in[4];
  const float* W2 = (const float*)d_in[5];
  const float* b2 = (const float*)d_in[6];
  const float* Wh = (const float*)d_in[7];
  const float* bh = (const float*)d_in[8];
  float* out = (float*)d_out;

  char* ws = (char*)d_ws;
  unsigned short* W1sw = (unsigned short*)(ws + WS_W1);
  unsigned short* W2sw = (unsigned short*)(ws + WS_W2);
  int* hist = (int*)(ws + WS_HIST);
  int* rank = (int*)(ws + WS_CUR);
  int* perm = (int*)(ws + WS_PERM);

  int B = in_sizes[1];   // 131072
  int nbH = (B + 255) / 256;

  hipMemsetAsync(hist, 0, 4096 * sizeof(int), stream);   // hist + rank_ctr
  combo_prep<<<nbH + 312 + 144, 256, 0, stream>>>(qd, ic, B, nbH, W1, W2,
                                                  hist, W1sw, W2sw);
  scatter2<<<(B + 255) / 256, 256, 0, stream>>>(qd, ic, B, hist, rank, perm);

  fused_qmlp8<<<B / BM, NT, 0, stream>>>(x, qd, ic, b1, b2, Wh, bh,
                                         W1sw, W2sw, perm, out);
}